// Round 12
// baseline (215.999 us; speedup 1.0000x reference)
//
#include <hip/hip_runtime.h>
#include <hip/hip_bf16.h>
#include <math.h>

// Problem constants
#define HIDDEN 1024
#define HEADS  16
#define HDIM   64
#define BATCH  2
#define SEQ    2048
#define ROWS   (BATCH*SEQ)   // 4096
#define BH     (BATCH*HEADS) // 32

typedef __attribute__((ext_vector_type(8))) short  short8;
typedef __attribute__((ext_vector_type(8))) __bf16 bf16x8;
typedef __attribute__((ext_vector_type(4))) float  f32x4;
typedef __attribute__((ext_vector_type(4))) unsigned int uint4v;

static __device__ __forceinline__ unsigned short f2bf(float f) {
    unsigned int u = __builtin_bit_cast(unsigned int, f);
    u += 0x7FFFu + ((u >> 16) & 1u);   // round-to-nearest-even
    return (unsigned short)(u >> 16);
}
static __device__ __forceinline__ float bf2f(unsigned short h) {
    unsigned int u = ((unsigned int)h) << 16;
    return __builtin_bit_cast(float, u);
}
static __device__ __forceinline__ f32x4 mfma16(short8 a, short8 b, f32x4 c) {
    return __builtin_amdgcn_mfma_f32_16x16x32_bf16(
        __builtin_bit_cast(bf16x8, a), __builtin_bit_cast(bf16x8, b), c, 0, 0, 0);
}
// async global->LDS, 16B per lane; lds dest = wave-uniform base + lane*16
static __device__ __forceinline__ void gl_lds16(const unsigned short* g, unsigned short* l) {
    __builtin_amdgcn_global_load_lds(
        (const __attribute__((address_space(1))) unsigned int*)g,
        (__attribute__((address_space(3))) unsigned int*)l, 16, 0, 0);
}

// ---------------------------------------------------------------- prep: x->bf16 + W->bf16^T + consts
// grid 5120: blocks [0,4096) convert x (+ mod/pos tables in first 8); [4096,5120) transpose W.
__global__ __launch_bounds__(256) void prep_kernel(
    const float* __restrict__ x, unsigned short* __restrict__ xb,
    const float* __restrict__ w0, const float* __restrict__ w1,
    const float* __restrict__ w2, const float* __restrict__ w3,
    unsigned short* __restrict__ wt,
    const float* __restrict__ qp, const float* __restrict__ qa,
    float* __restrict__ mod, float* __restrict__ mod2,
    float* __restrict__ posc, float* __restrict__ poss) {
    __shared__ unsigned short tile[64][72];
    const int bid = blockIdx.x;
    const int t = threadIdx.x;
    if (bid < 4096) {
        int i = (bid * 256 + t) * 4;
        float4 v = *(const float4*)(x + i);
        ushort4 o;
        o.x = f2bf(v.x); o.y = f2bf(v.y); o.z = f2bf(v.z); o.w = f2bf(v.w);
        *(ushort4*)(xb + i) = o;
        if (bid < 8) {
            int k = bid * 256 + t;
            if (k < HIDDEN) {
                float m = cosf(qp[k]) * qa[k];
                mod[k] = m;
                mod2[k] = m * m * 0.18033688011112042f;   // mod^2 * 0.125 * log2(e)
            }
            if (k < SEQ) {
                float ang = (float)k * (6.283185307179586f / (float)SEQ);
                posc[k] = cosf(ang);
                poss[k] = sinf(ang);
            }
        }
        return;
    }
    int rem = bid - 4096;
    int z = rem >> 8, r2 = rem & 255;
    int n0 = (r2 & 15) * 64, k0 = (r2 >> 4) * 64;
    const float* src = (z == 0) ? w0 : (z == 1) ? w1 : (z == 2) ? w2 : w3;
    unsigned short* dst = wt + (size_t)z * HIDDEN * HIDDEN;
    int cg = t & 15, r0 = t >> 4;
#pragma unroll
    for (int rr = 0; rr < 4; rr++) {
        int kl = r0 + rr * 16;
        float4 v = *(const float4*)(src + (size_t)(k0 + kl) * HIDDEN + n0 + cg * 4);
        tile[cg*4+0][kl] = f2bf(v.x);
        tile[cg*4+1][kl] = f2bf(v.y);
        tile[cg*4+2][kl] = f2bf(v.z);
        tile[cg*4+3][kl] = f2bf(v.w);
    }
    __syncthreads();
#pragma unroll
    for (int rr = 0; rr < 4; rr++) {
        int nl = r0 + rr * 16;
        ushort4 o;
        o.x = tile[nl][cg*4+0]; o.y = tile[nl][cg*4+1];
        o.z = tile[nl][cg*4+2]; o.w = tile[nl][cg*4+3];
        *(ushort4*)(dst + (size_t)(n0 + nl) * HIDDEN + k0 + cg * 4) = o;
    }
}

// ---------------------------------------------------------------- GEMM QKV fused: 128x64 tile, BK=64
// R26's kernel (K-loop identical to R23) + LDS-bounce vectorized C-write.
__global__ __launch_bounds__(256) void gemm_kernel(
    const unsigned short* __restrict__ A, const unsigned short* __restrict__ WtBase,
    unsigned short* __restrict__ CBase, const float* __restrict__ mod) {
    __shared__ unsigned short Alds[128 * 64];      // 16 KB
    __shared__ unsigned short Blds[3][64 * 64];    // 24 KB
    const int m0 = blockIdx.x * 128, n0 = blockIdx.y * 64;
    const int tid = threadIdx.x;
    const int wave = tid >> 6, lane = tid & 63, quad = lane >> 4, l15 = lane & 15;
    const int wr = wave >> 1, wc = wave & 1;
    const int srow = lane >> 3;
    const int schunk = (lane & 7) ^ (srow & 7);

    f32x4 acc[3][4][2];
    const f32x4 z4 = {0.f, 0.f, 0.f, 0.f};
#pragma unroll
    for (int z = 0; z < 3; z++)
#pragma unroll
        for (int i = 0; i < 4; i++)
#pragma unroll
            for (int j = 0; j < 2; j++) acc[z][i][j] = z4;

    for (int k0 = 0; k0 < HIDDEN; k0 += 64) {
#pragma unroll
        for (int p = 0; p < 4; p++) {
            int rbase = p * 32 + wave * 8;
            gl_lds16(A + (size_t)(m0 + rbase + srow) * HIDDEN + k0 + schunk * 8,
                     &Alds[rbase * 64]);
        }
#pragma unroll
        for (int z = 0; z < 3; z++) {
#pragma unroll
            for (int p = 0; p < 2; p++) {
                int rbase = p * 32 + wave * 8;
                gl_lds16(WtBase + (size_t)z * HIDDEN * HIDDEN
                             + (size_t)(n0 + rbase + srow) * HIDDEN + k0 + schunk * 8,
                         &Blds[z][rbase * 64]);
            }
        }
        __syncthreads();
        short8 aF[4][2];
#pragma unroll
        for (int h = 0; h < 2; h++)
#pragma unroll
            for (int i = 0; i < 4; i++) {
                int row = wr * 64 + i * 16 + l15;
                aF[i][h] = *(const short8*)(&Alds[row * 64 + ((h * 4 + quad) ^ (l15 & 7)) * 8]);
            }
#pragma unroll
        for (int z = 0; z < 3; z++) {
            short8 bF[2][2];
#pragma unroll
            for (int h = 0; h < 2; h++)
#pragma unroll
                for (int j = 0; j < 2; j++) {
                    int row = wc * 32 + j * 16 + l15;
                    bF[j][h] = *(const short8*)(&Blds[z][row * 64 + ((h * 4 + quad) ^ (l15 & 7)) * 8]);
                }
#pragma unroll
            for (int h = 0; h < 2; h++)
#pragma unroll
                for (int i = 0; i < 4; i++)
#pragma unroll
                    for (int j = 0; j < 2; j++)
                        acc[z][i][j] = mfma16(aF[i][h], bF[j][h], acc[z][i][j]);
        }
        __syncthreads();
    }

    // ---- epilogue: LDS-bounce vectorized C-write (per z; Alds is dead post-loop)
#pragma unroll
    for (int z = 0; z < 3; z++) {
        unsigned short* Cout = CBase + (size_t)z * ROWS * HIDDEN;
#pragma unroll
        for (int i = 0; i < 4; i++) {
            int rloc = wr * 64 + i * 16 + quad * 4;            // local row base
#pragma unroll
            for (int j = 0; j < 2; j++) {
                int nloc = wc * 32 + j * 16 + l15;             // local col
                float vm = (z == 2) ? mod[n0 + nloc] : 1.0f;
#pragma unroll
                for (int r = 0; r < 4; r++)
                    Alds[(rloc + r) * 64 + nloc] = f2bf(acc[z][i][j][r] * vm);
            }
        }
        __syncthreads();
        // 128 rows x 128B; each thread stores 16B: 8 threads cover one full line
#pragma unroll
        for (int pass = 0; pass < 4; pass++) {
            int idx = pass * 256 + tid;
            int row = idx >> 3, chunk = idx & 7;
            short8 v = *(const short8*)(&Alds[row * 64 + chunk * 8]);
            *(short8*)(&Cout[(size_t)(m0 + row) * HIDDEN + n0 + chunk * 8]) = v;
        }
        __syncthreads();   // Alds reused by next z
    }
}

// ---------------------------------------------------------------- GEMM O: 128x64 tile, BK=64
// grid (32,16) = 512 blocks = 2/CU. fp32 out.  (R23 proven version)
__global__ __launch_bounds__(256) void gemm_o_kernel(
    const unsigned short* __restrict__ A, const unsigned short* __restrict__ Bt,
    float* __restrict__ Out) {
    __shared__ unsigned short Alds[128 * 64];   // 16 KB
    __shared__ unsigned short Blds[64 * 64];    // 8 KB
    const int m0 = blockIdx.x * 128, n0 = blockIdx.y * 64;
    const int tid = threadIdx.x;
    const int wave = tid >> 6, lane = tid & 63, quad = lane >> 4, l15 = lane & 15;
    const int wr = wave >> 1, wc = wave & 1;
    const int srow = lane >> 3;
    const int schunk = (lane & 7) ^ (srow & 7);

    f32x4 acc[4][2];
    const f32x4 z4 = {0.f, 0.f, 0.f, 0.f};
#pragma unroll
    for (int i = 0; i < 4; i++)
#pragma unroll
        for (int j = 0; j < 2; j++) acc[i][j] = z4;

    for (int k0 = 0; k0 < HIDDEN; k0 += 64) {
#pragma unroll
        for (int p = 0; p < 4; p++) {
            int rbase = p * 32 + wave * 8;
            gl_lds16(A + (size_t)(m0 + rbase + srow) * HIDDEN + k0 + schunk * 8,
                     &Alds[rbase * 64]);
        }
#pragma unroll
        for (int p = 0; p < 2; p++) {
            int rbase = p * 32 + wave * 8;
            gl_lds16(Bt + (size_t)(n0 + rbase + srow) * HIDDEN + k0 + schunk * 8,
                     &Blds[rbase * 64]);
        }
        __syncthreads();
        short8 aF[4][2], bF[2][2];
#pragma unroll
        for (int h = 0; h < 2; h++) {
#pragma unroll
            for (int i = 0; i < 4; i++) {
                int row = wr * 64 + i * 16 + l15;
                aF[i][h] = *(const short8*)(&Alds[row * 64 + ((h * 4 + quad) ^ (l15 & 7)) * 8]);
            }
#pragma unroll
            for (int j = 0; j < 2; j++) {
                int row = wc * 32 + j * 16 + l15;
                bF[j][h] = *(const short8*)(&Blds[row * 64 + ((h * 4 + quad) ^ (l15 & 7)) * 8]);
            }
        }
#pragma unroll
        for (int h = 0; h < 2; h++)
#pragma unroll
            for (int i = 0; i < 4; i++)
#pragma unroll
                for (int j = 0; j < 2; j++)
                    acc[i][j] = mfma16(aF[i][h], bF[j][h], acc[i][j]);
        __syncthreads();
    }

#pragma unroll
    for (int i = 0; i < 4; i++) {
        int mbase = m0 + wr * 64 + i * 16 + quad * 4;
#pragma unroll
        for (int j = 0; j < 2; j++) {
            int n = n0 + wc * 32 + j * 16 + l15;
#pragma unroll
            for (int r = 0; r < 4; r++)
                Out[(size_t)(mbase + r) * HIDDEN + n] = acc[i][j][r];
        }
    }
}

// ---------------------------------------------------------------- V shift + transpose (mod pre-folded in gemm)
// Vpt[bh][d][s] = (Vm[s][d] + Vm[(s+1)%S][d])/sqrt2. grid = (bh=32, stile=32).
__global__ __launch_bounds__(256) void vshift_kernel(const unsigned short* __restrict__ Vm,
                                                     unsigned short* __restrict__ Vpt) {
    __shared__ unsigned short lds[65][72];
    int bh = blockIdx.x, b = bh >> 4, h = bh & 15;
    int s0 = blockIdx.y * 64;
    int t = threadIdx.x;
    int cg = t & 15, r0 = t >> 4;
#pragma unroll
    for (int rr = 0; rr < 4; rr++) {
        int row = r0 + rr * 16;
        ushort4 v = *(const ushort4*)(Vm + ((size_t)(b * SEQ + s0 + row)) * HIDDEN + h * 64 + cg * 4);
        *(ushort4*)(&lds[row][cg * 4]) = v;
    }
    if (t < 16) {
        int srow = (s0 + 64) & (SEQ - 1);
        ushort4 v = *(const ushort4*)(Vm + ((size_t)(b * SEQ + srow)) * HIDDEN + h * 64 + t * 4);
        *(ushort4*)(&lds[64][t * 4]) = v;
    }
    __syncthreads();
    int d = t & 63, sb = (t >> 6) * 16;
    unsigned short outv[16];
#pragma unroll
    for (int k = 0; k < 16; k++) {
        float a = bf2f(lds[sb + k][d]), bb = bf2f(lds[sb + k + 1][d]);
        outv[k] = f2bf((a + bb) * 0.7071067811865476f);
    }
    unsigned short* dst = Vpt + ((size_t)bh * 64 + d) * SEQ + s0 + sb;
#pragma unroll
    for (int k = 0; k < 16; k += 4) {
        ushort4 o; o.x = outv[k]; o.y = outv[k+1]; o.z = outv[k+2]; o.w = outv[k+3];
        *(ushort4*)(dst + k) = o;
    }
}

// ---------------------------------------------------------------- flash attention (KT=128)
// R27 = R23/R26's proven kernel + ONE change: wave-rotated chunk order
// (chunk = (cc + w4) & 3). Chunks are commutative sums; all chunks staged before the
// barrier -> any order race-free. De-phases the 4 q-waves per key half so DS/VALU/MFMA
// demand overlaps instead of hitting each pipe in block-wide lockstep (pipe-busy sums
// to ~100% of runtime in R26 -> phases are serialized).
#define KT 128
__global__ __launch_bounds__(512, 4) void attn_kernel(const unsigned short* __restrict__ Cq,
                                                      const unsigned short* __restrict__ Ck,
                                                      const unsigned short* __restrict__ Vpt,
                                                      unsigned short* __restrict__ Ob,
                                                      const float* __restrict__ mod2,
                                                      const float* __restrict__ posc,
                                                      const float* __restrict__ poss) {
    __shared__ unsigned short sbuf[2 * KT * 64 + 2 * 64 * KT];   // 64 KB (K[2] then V[2])
    unsigned short* KldsB  = sbuf;                 // [kh][KT*64]
    unsigned short* VtldsB = sbuf + 2 * KT * 64;   // [kh][64*KT]
    const int bh = blockIdx.x;
    const int b = bh >> 4, h = bh & 15;
    const int tid = threadIdx.x, wave = tid >> 6, lane = tid & 63;
    const int kh = wave >> 2, w4 = wave & 3;
    const int quad = lane >> 4, l15 = lane & 15;
    const int q0 = blockIdx.y * 128 + w4 * 32;

    // Q fragments (mod^2*scale*log2e folded); MFMA B operand. g=2 (R16 structure).
    short8 qf[2][2];
#pragma unroll
    for (int g = 0; g < 2; g++) {
        int ss = q0 + g * 16 + l15;
        const unsigned short* crow = Cq + ((size_t)(b * SEQ + ss)) * HIDDEN + h * 64;
#pragma unroll
        for (int kk = 0; kk < 2; kk++) {
            int bd = kk * 32 + quad * 8;
            short8 u = *(const short8*)(crow + bd);
            short8 q;
#pragma unroll
            for (int e = 0; e < 8; e++)
                q[e] = (short)f2bf(bf2f((unsigned short)u[e]) * mod2[h * 64 + bd + e]);
            qf[g][kk] = q;
        }
    }
    float ci_[2], si_[2];
#pragma unroll
    for (int g = 0; g < 2; g++) {
        ci_[g] = posc[q0 + g * 16 + l15];
        si_[g] = poss[q0 + g * 16 + l15];
    }

    short8 ones;
#pragma unroll
    for (int e = 0; e < 8; e++) ones[e] = (short)0x3F80;

    const f32x4 z4 = {0.f, 0.f, 0.f, 0.f};
    f32x4 acc[2][4], accden[2];
#pragma unroll
    for (int g = 0; g < 2; g++) {
#pragma unroll
        for (int dt = 0; dt < 4; dt++) acc[g][dt] = z4;
        accden[g] = z4;
    }

    const unsigned short* Kbh = Ck  + ((size_t)b * SEQ) * HIDDEN + h * 64;   // row stride HIDDEN
    const unsigned short* Vbh = Vpt + (size_t)bh * 64 * SEQ;                 // row stride SEQ

    // All 8 waves stage both halves' tiles (R20's proven swizzle formulas, per tile):
    auto stage = [&](int it) {
#pragma unroll
        for (int t = 0; t < 2; t++) {
            const int j = t * (SEQ / 2) + it * KT;
            unsigned short* Kd = KldsB  + t * KT * 64;
            unsigned short* Vd = VtldsB + t * 64 * KT;
#pragma unroll
            for (int p = 0; p < 2; p++) {           // K: 128 rows x 64 d, 8 rows/instr/wave
                int rb = p * 64 + wave * 8;
                int r  = rb + (lane >> 3);
                int c  = (lane & 7) ^ (r & 7);
                gl_lds16(Kbh + (size_t)(j + r) * HIDDEN + c * 8, Kd + rb * 64);
            }
#pragma unroll
            for (int p = 0; p < 2; p++) {           // V^T: 64 d-rows x 128 keys, 4 rows/instr/wave
                int rb = p * 32 + wave * 4;
                int r  = rb + (lane >> 4);
                int c  = (lane & 15) ^ (r & 15);
                gl_lds16(Vbh + (size_t)r * SEQ + j + c * 8, Vd + rb * KT);
            }
        }
    };

    const unsigned short* Kme = KldsB  + kh * KT * 64;
    const unsigned short* Vme = VtldsB + kh * 64 * KT;
    const int NIT = (SEQ / 2) / KT;   // 8 iterations per key half
    for (int it = 0; it < NIT; it++) {
        stage(it);
        __syncthreads();                 // own vmcnt(0) drained + all waves -> tiles ready
        const int jbase = kh * (SEQ / 2) + it * KT;

        // 4 chunks of 32 keys, wave-rotated order (commutative sums; staged pre-barrier)
#pragma unroll
        for (int cc = 0; cc < 4; cc++) {
            const int chunk = (cc + w4) & 3;
            const int jb = jbase + chunk * 32 + quad * 4;
            f32x4 cjA[2], sjA[2];
            cjA[0] = *(const f32x4*)(posc + jb);
            sjA[0] = *(const f32x4*)(poss + jb);
            cjA[1] = *(const f32x4*)(posc + jb + 16);
            sjA[1] = *(const f32x4*)(poss + jb + 16);

            f32x4 sc[2][2];   // [g][t2i]; C row = key quad*4+r, col = q l15
            sc[0][0] = z4; sc[0][1] = z4; sc[1][0] = z4; sc[1][1] = z4;
            __builtin_amdgcn_s_setprio(1);
#pragma unroll
            for (int t2i = 0; t2i < 2; t2i++) {
                int tt = chunk * 2 + t2i;
#pragma unroll
                for (int kk = 0; kk < 2; kk++) {
                    int ch = (kk * 4 + quad) ^ (l15 & 7);
                    short8 kf = *(const short8*)(Kme + (tt * 16 + l15) * 64 + ch * 8);
                    sc[0][t2i] = mfma16(kf, qf[0][kk], sc[0][t2i]);
                    sc[1][t2i] = mfma16(kf, qf[1][kk], sc[1][t2i]);
                }
            }
            __builtin_amdgcn_s_setprio(0);

            short8 pa[2];
#pragma unroll
            for (int g = 0; g < 2; g++) {
                unsigned int w_[4];
#pragma unroll
                for (int t2i = 0; t2i < 2; t2i++) {
#pragma unroll
                    for (int hp = 0; hp < 2; hp++) {
                        float wl = ci_[g] * cjA[t2i][2 * hp]     + si_[g] * sjA[t2i][2 * hp];
                        float wh = ci_[g] * cjA[t2i][2 * hp + 1] + si_[g] * sjA[t2i][2 * hp + 1];
                        float pl = __builtin_amdgcn_exp2f(sc[g][t2i][2 * hp]     * wl);
                        float ph = __builtin_amdgcn_exp2f(sc[g][t2i][2 * hp + 1] * wh);
                        unsigned int w;
                        asm("v_cvt_pk_bf16_f32 %0, %1, %2" : "=v"(w) : "v"(pl), "v"(ph));
                        w_[t2i * 2 + hp] = w;
                    }
                }
                auto t02 = __builtin_amdgcn_permlane32_swap(w_[0], w_[2], false, false);
                auto a02 = __builtin_amdgcn_permlane16_swap(t02[0], t02[1], false, false);
                auto t13 = __builtin_amdgcn_permlane32_swap(w_[1], w_[3], false, false);
                auto a13 = __builtin_amdgcn_permlane16_swap(t13[0], t13[1], false, false);
                uint4v pword;
                pword[0] = a02[0]; pword[1] = a13[0]; pword[2] = a02[1]; pword[3] = a13[1];
                pa[g] = __builtin_bit_cast(short8, pword);   // A[row=q l15][k=quad*8+e]
                accden[g] = mfma16(pa[g], ones, accden[g]);
            }

            __builtin_amdgcn_s_setprio(1);
#pragma unroll
            for (int dt = 0; dt < 4; dt++) {
                int ch = (chunk * 4 + quad) ^ l15;
                short8 vb = *(const short8*)(Vme + (dt * 16 + l15) * KT + ch * 8);
                acc[0][dt] = mfma16(pa[0], vb, acc[0][dt]);
                acc[1][dt] = mfma16(pa[1], vb, acc[1][dt]);
            }
            __builtin_amdgcn_s_setprio(0);
        }
        __syncthreads();                 // all reads done before next stage overwrites
    }

    // ---- key-half combine through (dead) staging LDS; stride 41 floats = conflict-free
    float* cmb = (float*)sbuf;
    const int slot = (w4 * 64 + lane) * 41;
    if (kh == 1) {
#pragma unroll
        for (int g = 0; g < 2; g++) {
#pragma unroll
            for (int dt = 0; dt < 4; dt++)
#pragma unroll
                for (int r = 0; r < 4; r++)
                    cmb[slot + g * 16 + dt * 4 + r] = acc[g][dt][r];
#pragma unroll
            for (int r = 0; r < 4; r++)
                cmb[slot + 32 + g * 4 + r] = accden[g][r];
        }
    }
    __syncthreads();
    if (kh == 0) {
#pragma unroll
        for (int g = 0; g < 2; g++) {
#pragma unroll
            for (int dt = 0; dt < 4; dt++)
#pragma unroll
                for (int r = 0; r < 4; r++)
                    acc[g][dt][r] += cmb[slot + g * 16 + dt * 4 + r];
#pragma unroll
            for (int r = 0; r < 4; r++)
                accden[g][r] += cmb[slot + 32 + g * 4 + r];
        }
#pragma unroll
        for (int g = 0; g < 2; g++) {
            float rinv[4];
#pragma unroll
            for (int r = 0; r < 4; r++) rinv[r] = 1.0f / accden[g][r];
#pragma unroll
            for (int dt = 0; dt < 4; dt++) {
#pragma unroll
                for (int r = 0; r < 4; r++) {
                    int q = q0 + g * 16 + quad * 4 + r;
                    int d = dt * 16 + l15;
                    Ob[((size_t)(b * SEQ + q)) * HIDDEN + h * 64 + d] = f2bf(acc[g][dt][r] * rinv[r]);
                }
            }
        }
    }
}

// ---------------------------------------------------------------- launch
extern "C" void kernel_launch(void* const* d_in, const int* in_sizes, int n_in,
                              void* d_out, int out_size, void* d_ws, size_t ws_size,
                              hipStream_t stream) {
    const float* x  = (const float*)d_in[0];
    const float* Wq = (const float*)d_in[1];
    const float* Wk = (const float*)d_in[2];
    const float* Wv = (const float*)d_in[3];
    const float* Wo = (const float*)d_in[4];
    const float* qp = (const float*)d_in[5];
    const float* qa = (const float*)d_in[6];
    char* ws = (char*)d_ws;

    unsigned short* Xb  = (unsigned short*)(ws);                      // 8 MB (reused as Ob)
    unsigned short* Wt  = (unsigned short*)(ws + (size_t)( 8 << 20)); // 8 MB (4 x 2MB)
    unsigned short* Cq  = (unsigned short*)(ws + (size_t)(16 << 20)); // 8 MB
    unsigned short* Ck  = (unsigned short*)(ws + (size_t)(24 << 20)); // 8 MB
    unsigned short* Cv  = (unsigned short*)(ws + (size_t)(32 << 20)); // 8 MB (holds V*mod)
    unsigned short* Vpt = (unsigned short*)(ws + (size_t)(40 << 20)); // 8 MB
    float* mod  = (float*)(ws + (size_t)(48 << 20));
    float* mod2 = mod + 1024;
    float* posc = mod2 + 1024;
    float* poss = posc + 2048;
    float* out  = (float*)d_out;

    prep_kernel<<<5120, 256, 0, stream>>>(x, Xb, Wq, Wk, Wv, Wo, Wt,
                                          qp, qa, mod, mod2, posc, poss);
    gemm_kernel<<<dim3(32, 16), 256, 0, stream>>>(Xb, Wt, Cq, mod);  // fused -> Cq,Ck,Cv(modded)
    vshift_kernel<<<dim3(32, 32), 256, 0, stream>>>(Cv, Vpt);
    attn_kernel<<<dim3(32, 16), 512, 0, stream>>>(Cq, Ck, Vpt, Xb /*Ob*/, mod2, posc, poss);
    gemm_o_kernel<<<dim3(32, 16), 256, 0, stream>>>(Xb, Wt + (size_t)3 * HIDDEN * HIDDEN, out);
}

// Round 13
// 205.003 us; speedup vs baseline: 1.0536x; 1.0536x over previous
//
#include <hip/hip_runtime.h>
#include <hip/hip_bf16.h>
#include <math.h>

// Problem constants
#define HIDDEN 1024
#define HEADS  16
#define HDIM   64
#define BATCH  2
#define SEQ    2048
#define ROWS   (BATCH*SEQ)   // 4096
#define BH     (BATCH*HEADS) // 32

typedef __attribute__((ext_vector_type(8))) short  short8;
typedef __attribute__((ext_vector_type(8))) __bf16 bf16x8;
typedef __attribute__((ext_vector_type(4))) float  f32x4;
typedef __attribute__((ext_vector_type(4))) unsigned int uint4v;

static __device__ __forceinline__ unsigned short f2bf(float f) {
    unsigned int u = __builtin_bit_cast(unsigned int, f);
    u += 0x7FFFu + ((u >> 16) & 1u);   // round-to-nearest-even
    return (unsigned short)(u >> 16);
}
static __device__ __forceinline__ float bf2f(unsigned short h) {
    unsigned int u = ((unsigned int)h) << 16;
    return __builtin_bit_cast(float, u);
}
static __device__ __forceinline__ f32x4 mfma16(short8 a, short8 b, f32x4 c) {
    return __builtin_amdgcn_mfma_f32_16x16x32_bf16(
        __builtin_bit_cast(bf16x8, a), __builtin_bit_cast(bf16x8, b), c, 0, 0, 0);
}
// async global->LDS, 16B per lane; lds dest = wave-uniform base + lane*16
static __device__ __forceinline__ void gl_lds16(const unsigned short* g, unsigned short* l) {
    __builtin_amdgcn_global_load_lds(
        (const __attribute__((address_space(1))) unsigned int*)g,
        (__attribute__((address_space(3))) unsigned int*)l, 16, 0, 0);
}

// ---------------------------------------------------------------- prep: x->bf16 + W->bf16^T + consts
// grid 5120: blocks [0,4096) convert x (+ mod/pos tables in first 8); [4096,5120) transpose W.
__global__ __launch_bounds__(256) void prep_kernel(
    const float* __restrict__ x, unsigned short* __restrict__ xb,
    const float* __restrict__ w0, const float* __restrict__ w1,
    const float* __restrict__ w2, const float* __restrict__ w3,
    unsigned short* __restrict__ wt,
    const float* __restrict__ qp, const float* __restrict__ qa,
    float* __restrict__ mod, float* __restrict__ mod2,
    float* __restrict__ posc, float* __restrict__ poss) {
    __shared__ unsigned short tile[64][72];
    const int bid = blockIdx.x;
    const int t = threadIdx.x;
    if (bid < 4096) {
        int i = (bid * 256 + t) * 4;
        float4 v = *(const float4*)(x + i);
        ushort4 o;
        o.x = f2bf(v.x); o.y = f2bf(v.y); o.z = f2bf(v.z); o.w = f2bf(v.w);
        *(ushort4*)(xb + i) = o;
        if (bid < 8) {
            int k = bid * 256 + t;
            if (k < HIDDEN) {
                float m = cosf(qp[k]) * qa[k];
                mod[k] = m;
                mod2[k] = m * m * 0.18033688011112042f;   // mod^2 * 0.125 * log2(e)
            }
            if (k < SEQ) {
                float ang = (float)k * (6.283185307179586f / (float)SEQ);
                posc[k] = cosf(ang);
                poss[k] = sinf(ang);
            }
        }
        return;
    }
    int rem = bid - 4096;
    int z = rem >> 8, r2 = rem & 255;
    int n0 = (r2 & 15) * 64, k0 = (r2 >> 4) * 64;
    const float* src = (z == 0) ? w0 : (z == 1) ? w1 : (z == 2) ? w2 : w3;
    unsigned short* dst = wt + (size_t)z * HIDDEN * HIDDEN;
    int cg = t & 15, r0 = t >> 4;
#pragma unroll
    for (int rr = 0; rr < 4; rr++) {
        int kl = r0 + rr * 16;
        float4 v = *(const float4*)(src + (size_t)(k0 + kl) * HIDDEN + n0 + cg * 4);
        tile[cg*4+0][kl] = f2bf(v.x);
        tile[cg*4+1][kl] = f2bf(v.y);
        tile[cg*4+2][kl] = f2bf(v.z);
        tile[cg*4+3][kl] = f2bf(v.w);
    }
    __syncthreads();
#pragma unroll
    for (int rr = 0; rr < 4; rr++) {
        int nl = r0 + rr * 16;
        ushort4 o;
        o.x = tile[nl][cg*4+0]; o.y = tile[nl][cg*4+1];
        o.z = tile[nl][cg*4+2]; o.w = tile[nl][cg*4+3];
        *(ushort4*)(dst + (size_t)(n0 + nl) * HIDDEN + k0 + cg * 4) = o;
    }
}

// ---------------------------------------------------------------- GEMM QKV fused: 128x64 tile, BK=64
// R26's kernel (K-loop identical to R23) + LDS-bounce vectorized C-write.
__global__ __launch_bounds__(256) void gemm_kernel(
    const unsigned short* __restrict__ A, const unsigned short* __restrict__ WtBase,
    unsigned short* __restrict__ CBase, const float* __restrict__ mod) {
    __shared__ unsigned short Alds[128 * 64];      // 16 KB
    __shared__ unsigned short Blds[3][64 * 64];    // 24 KB
    const int m0 = blockIdx.x * 128, n0 = blockIdx.y * 64;
    const int tid = threadIdx.x;
    const int wave = tid >> 6, lane = tid & 63, quad = lane >> 4, l15 = lane & 15;
    const int wr = wave >> 1, wc = wave & 1;
    const int srow = lane >> 3;
    const int schunk = (lane & 7) ^ (srow & 7);

    f32x4 acc[3][4][2];
    const f32x4 z4 = {0.f, 0.f, 0.f, 0.f};
#pragma unroll
    for (int z = 0; z < 3; z++)
#pragma unroll
        for (int i = 0; i < 4; i++)
#pragma unroll
            for (int j = 0; j < 2; j++) acc[z][i][j] = z4;

    for (int k0 = 0; k0 < HIDDEN; k0 += 64) {
#pragma unroll
        for (int p = 0; p < 4; p++) {
            int rbase = p * 32 + wave * 8;
            gl_lds16(A + (size_t)(m0 + rbase + srow) * HIDDEN + k0 + schunk * 8,
                     &Alds[rbase * 64]);
        }
#pragma unroll
        for (int z = 0; z < 3; z++) {
#pragma unroll
            for (int p = 0; p < 2; p++) {
                int rbase = p * 32 + wave * 8;
                gl_lds16(WtBase + (size_t)z * HIDDEN * HIDDEN
                             + (size_t)(n0 + rbase + srow) * HIDDEN + k0 + schunk * 8,
                         &Blds[z][rbase * 64]);
            }
        }
        __syncthreads();
        short8 aF[4][2];
#pragma unroll
        for (int h = 0; h < 2; h++)
#pragma unroll
            for (int i = 0; i < 4; i++) {
                int row = wr * 64 + i * 16 + l15;
                aF[i][h] = *(const short8*)(&Alds[row * 64 + ((h * 4 + quad) ^ (l15 & 7)) * 8]);
            }
#pragma unroll
        for (int z = 0; z < 3; z++) {
            short8 bF[2][2];
#pragma unroll
            for (int h = 0; h < 2; h++)
#pragma unroll
                for (int j = 0; j < 2; j++) {
                    int row = wc * 32 + j * 16 + l15;
                    bF[j][h] = *(const short8*)(&Blds[z][row * 64 + ((h * 4 + quad) ^ (l15 & 7)) * 8]);
                }
#pragma unroll
            for (int h = 0; h < 2; h++)
#pragma unroll
                for (int i = 0; i < 4; i++)
#pragma unroll
                    for (int j = 0; j < 2; j++)
                        acc[z][i][j] = mfma16(aF[i][h], bF[j][h], acc[z][i][j]);
        }
        __syncthreads();
    }

    // ---- epilogue: LDS-bounce vectorized C-write (per z; Alds is dead post-loop)
#pragma unroll
    for (int z = 0; z < 3; z++) {
        unsigned short* Cout = CBase + (size_t)z * ROWS * HIDDEN;
#pragma unroll
        for (int i = 0; i < 4; i++) {
            int rloc = wr * 64 + i * 16 + quad * 4;            // local row base
#pragma unroll
            for (int j = 0; j < 2; j++) {
                int nloc = wc * 32 + j * 16 + l15;             // local col
                float vm = (z == 2) ? mod[n0 + nloc] : 1.0f;
#pragma unroll
                for (int r = 0; r < 4; r++)
                    Alds[(rloc + r) * 64 + nloc] = f2bf(acc[z][i][j][r] * vm);
            }
        }
        __syncthreads();
        // 128 rows x 128B; each thread stores 16B: 8 threads cover one full line
#pragma unroll
        for (int pass = 0; pass < 4; pass++) {
            int idx = pass * 256 + tid;
            int row = idx >> 3, chunk = idx & 7;
            short8 v = *(const short8*)(&Alds[row * 64 + chunk * 8]);
            *(short8*)(&Cout[(size_t)(m0 + row) * HIDDEN + n0 + chunk * 8]) = v;
        }
        __syncthreads();   // Alds reused by next z
    }
}

// ---------------------------------------------------------------- GEMM O: 128x64 tile, BK=64
// grid (32,16) = 512 blocks = 2/CU. fp32 out.  (R23 proven version)
__global__ __launch_bounds__(256) void gemm_o_kernel(
    const unsigned short* __restrict__ A, const unsigned short* __restrict__ Bt,
    float* __restrict__ Out) {
    __shared__ unsigned short Alds[128 * 64];   // 16 KB
    __shared__ unsigned short Blds[64 * 64];    // 8 KB
    const int m0 = blockIdx.x * 128, n0 = blockIdx.y * 64;
    const int tid = threadIdx.x;
    const int wave = tid >> 6, lane = tid & 63, quad = lane >> 4, l15 = lane & 15;
    const int wr = wave >> 1, wc = wave & 1;
    const int srow = lane >> 3;
    const int schunk = (lane & 7) ^ (srow & 7);

    f32x4 acc[4][2];
    const f32x4 z4 = {0.f, 0.f, 0.f, 0.f};
#pragma unroll
    for (int i = 0; i < 4; i++)
#pragma unroll
        for (int j = 0; j < 2; j++) acc[i][j] = z4;

    for (int k0 = 0; k0 < HIDDEN; k0 += 64) {
#pragma unroll
        for (int p = 0; p < 4; p++) {
            int rbase = p * 32 + wave * 8;
            gl_lds16(A + (size_t)(m0 + rbase + srow) * HIDDEN + k0 + schunk * 8,
                     &Alds[rbase * 64]);
        }
#pragma unroll
        for (int p = 0; p < 2; p++) {
            int rbase = p * 32 + wave * 8;
            gl_lds16(Bt + (size_t)(n0 + rbase + srow) * HIDDEN + k0 + schunk * 8,
                     &Blds[rbase * 64]);
        }
        __syncthreads();
        short8 aF[4][2], bF[2][2];
#pragma unroll
        for (int h = 0; h < 2; h++) {
#pragma unroll
            for (int i = 0; i < 4; i++) {
                int row = wr * 64 + i * 16 + l15;
                aF[i][h] = *(const short8*)(&Alds[row * 64 + ((h * 4 + quad) ^ (l15 & 7)) * 8]);
            }
#pragma unroll
            for (int j = 0; j < 2; j++) {
                int row = wc * 32 + j * 16 + l15;
                bF[j][h] = *(const short8*)(&Blds[row * 64 + ((h * 4 + quad) ^ (l15 & 7)) * 8]);
            }
        }
#pragma unroll
        for (int h = 0; h < 2; h++)
#pragma unroll
            for (int i = 0; i < 4; i++)
#pragma unroll
                for (int j = 0; j < 2; j++)
                    acc[i][j] = mfma16(aF[i][h], bF[j][h], acc[i][j]);
        __syncthreads();
    }

#pragma unroll
    for (int i = 0; i < 4; i++) {
        int mbase = m0 + wr * 64 + i * 16 + quad * 4;
#pragma unroll
        for (int j = 0; j < 2; j++) {
            int n = n0 + wc * 32 + j * 16 + l15;
#pragma unroll
            for (int r = 0; r < 4; r++)
                Out[(size_t)(mbase + r) * HIDDEN + n] = acc[i][j][r];
        }
    }
}

// ---------------------------------------------------------------- V shift + transpose (mod pre-folded in gemm)
// Vpt[bh][d][s] = (Vm[s][d] + Vm[(s+1)%S][d])/sqrt2. grid = (bh=32, stile=32).
__global__ __launch_bounds__(256) void vshift_kernel(const unsigned short* __restrict__ Vm,
                                                     unsigned short* __restrict__ Vpt) {
    __shared__ unsigned short lds[65][72];
    int bh = blockIdx.x, b = bh >> 4, h = bh & 15;
    int s0 = blockIdx.y * 64;
    int t = threadIdx.x;
    int cg = t & 15, r0 = t >> 4;
#pragma unroll
    for (int rr = 0; rr < 4; rr++) {
        int row = r0 + rr * 16;
        ushort4 v = *(const ushort4*)(Vm + ((size_t)(b * SEQ + s0 + row)) * HIDDEN + h * 64 + cg * 4);
        *(ushort4*)(&lds[row][cg * 4]) = v;
    }
    if (t < 16) {
        int srow = (s0 + 64) & (SEQ - 1);
        ushort4 v = *(const ushort4*)(Vm + ((size_t)(b * SEQ + srow)) * HIDDEN + h * 64 + t * 4);
        *(ushort4*)(&lds[64][t * 4]) = v;
    }
    __syncthreads();
    int d = t & 63, sb = (t >> 6) * 16;
    unsigned short outv[16];
#pragma unroll
    for (int k = 0; k < 16; k++) {
        float a = bf2f(lds[sb + k][d]), bb = bf2f(lds[sb + k + 1][d]);
        outv[k] = f2bf((a + bb) * 0.7071067811865476f);
    }
    unsigned short* dst = Vpt + ((size_t)bh * 64 + d) * SEQ + s0 + sb;
#pragma unroll
    for (int k = 0; k < 16; k += 4) {
        ushort4 o; o.x = outv[k]; o.y = outv[k+1]; o.z = outv[k+2]; o.w = outv[k+3];
        *(ushort4*)(dst + k) = o;
    }
}

// ---------------------------------------------------------------- flash attention (KT=128)
// R23/R26 (proven, 72.0-72.5 us): key-split in block. 512 threads = 8 waves; wave = (kh, w4).
// Wave-pair (w4, w4+4) shares 32 q-rows; kh picks key half. Linear-sum softmax ->
// partials add exactly. LDS 64 KB -> 2 blocks/CU = 16 waves/CU, 32 q/wave DS economy.
// FROZEN: R17/R21/R24 restructures failed; R19 reorder null; R27 chunk-rotation −15%
// (lockstep L2 reuse beats de-phasing). In-order chunk loop is required.
#define KT 128
__global__ __launch_bounds__(512, 4) void attn_kernel(const unsigned short* __restrict__ Cq,
                                                      const unsigned short* __restrict__ Ck,
                                                      const unsigned short* __restrict__ Vpt,
                                                      unsigned short* __restrict__ Ob,
                                                      const float* __restrict__ mod2,
                                                      const float* __restrict__ posc,
                                                      const float* __restrict__ poss) {
    __shared__ unsigned short sbuf[2 * KT * 64 + 2 * 64 * KT];   // 64 KB (K[2] then V[2])
    unsigned short* KldsB  = sbuf;                 // [kh][KT*64]
    unsigned short* VtldsB = sbuf + 2 * KT * 64;   // [kh][64*KT]
    const int bh = blockIdx.x;
    const int b = bh >> 4, h = bh & 15;
    const int tid = threadIdx.x, wave = tid >> 6, lane = tid & 63;
    const int kh = wave >> 2, w4 = wave & 3;
    const int quad = lane >> 4, l15 = lane & 15;
    const int q0 = blockIdx.y * 128 + w4 * 32;

    // Q fragments (mod^2*scale*log2e folded); MFMA B operand. g=2 (R16 structure).
    short8 qf[2][2];
#pragma unroll
    for (int g = 0; g < 2; g++) {
        int ss = q0 + g * 16 + l15;
        const unsigned short* crow = Cq + ((size_t)(b * SEQ + ss)) * HIDDEN + h * 64;
#pragma unroll
        for (int kk = 0; kk < 2; kk++) {
            int bd = kk * 32 + quad * 8;
            short8 u = *(const short8*)(crow + bd);
            short8 q;
#pragma unroll
            for (int e = 0; e < 8; e++)
                q[e] = (short)f2bf(bf2f((unsigned short)u[e]) * mod2[h * 64 + bd + e]);
            qf[g][kk] = q;
        }
    }
    float ci_[2], si_[2];
#pragma unroll
    for (int g = 0; g < 2; g++) {
        ci_[g] = posc[q0 + g * 16 + l15];
        si_[g] = poss[q0 + g * 16 + l15];
    }

    short8 ones;
#pragma unroll
    for (int e = 0; e < 8; e++) ones[e] = (short)0x3F80;

    const f32x4 z4 = {0.f, 0.f, 0.f, 0.f};
    f32x4 acc[2][4], accden[2];
#pragma unroll
    for (int g = 0; g < 2; g++) {
#pragma unroll
        for (int dt = 0; dt < 4; dt++) acc[g][dt] = z4;
        accden[g] = z4;
    }

    const unsigned short* Kbh = Ck  + ((size_t)b * SEQ) * HIDDEN + h * 64;   // row stride HIDDEN
    const unsigned short* Vbh = Vpt + (size_t)bh * 64 * SEQ;                 // row stride SEQ

    // All 8 waves stage both halves' tiles (R20's proven swizzle formulas, per tile):
    auto stage = [&](int it) {
#pragma unroll
        for (int t = 0; t < 2; t++) {
            const int j = t * (SEQ / 2) + it * KT;
            unsigned short* Kd = KldsB  + t * KT * 64;
            unsigned short* Vd = VtldsB + t * 64 * KT;
#pragma unroll
            for (int p = 0; p < 2; p++) {           // K: 128 rows x 64 d, 8 rows/instr/wave
                int rb = p * 64 + wave * 8;
                int r  = rb + (lane >> 3);
                int c  = (lane & 7) ^ (r & 7);
                gl_lds16(Kbh + (size_t)(j + r) * HIDDEN + c * 8, Kd + rb * 64);
            }
#pragma unroll
            for (int p = 0; p < 2; p++) {           // V^T: 64 d-rows x 128 keys, 4 rows/instr/wave
                int rb = p * 32 + wave * 4;
                int r  = rb + (lane >> 4);
                int c  = (lane & 15) ^ (r & 15);
                gl_lds16(Vbh + (size_t)r * SEQ + j + c * 8, Vd + rb * KT);
            }
        }
    };

    const unsigned short* Kme = KldsB  + kh * KT * 64;
    const unsigned short* Vme = VtldsB + kh * 64 * KT;
    const int NIT = (SEQ / 2) / KT;   // 8 iterations per key half
    for (int it = 0; it < NIT; it++) {
        stage(it);
        __syncthreads();                 // own vmcnt(0) drained + all waves -> tiles ready
        const int jbase = kh * (SEQ / 2) + it * KT;

        // 4 chunks of 32 keys: QK (swapped operands) -> in-reg P -> PV   (R16 proven body)
#pragma unroll
        for (int chunk = 0; chunk < 4; chunk++) {
            const int jb = jbase + chunk * 32 + quad * 4;
            f32x4 cjA[2], sjA[2];
            cjA[0] = *(const f32x4*)(posc + jb);
            sjA[0] = *(const f32x4*)(poss + jb);
            cjA[1] = *(const f32x4*)(posc + jb + 16);
            sjA[1] = *(const f32x4*)(poss + jb + 16);

            f32x4 sc[2][2];   // [g][t2i]; C row = key quad*4+r, col = q l15
            sc[0][0] = z4; sc[0][1] = z4; sc[1][0] = z4; sc[1][1] = z4;
            __builtin_amdgcn_s_setprio(1);
#pragma unroll
            for (int t2i = 0; t2i < 2; t2i++) {
                int tt = chunk * 2 + t2i;
#pragma unroll
                for (int kk = 0; kk < 2; kk++) {
                    int ch = (kk * 4 + quad) ^ (l15 & 7);
                    short8 kf = *(const short8*)(Kme + (tt * 16 + l15) * 64 + ch * 8);
                    sc[0][t2i] = mfma16(kf, qf[0][kk], sc[0][t2i]);
                    sc[1][t2i] = mfma16(kf, qf[1][kk], sc[1][t2i]);
                }
            }
            __builtin_amdgcn_s_setprio(0);

            short8 pa[2];
#pragma unroll
            for (int g = 0; g < 2; g++) {
                unsigned int w_[4];
#pragma unroll
                for (int t2i = 0; t2i < 2; t2i++) {
#pragma unroll
                    for (int hp = 0; hp < 2; hp++) {
                        float wl = ci_[g] * cjA[t2i][2 * hp]     + si_[g] * sjA[t2i][2 * hp];
                        float wh = ci_[g] * cjA[t2i][2 * hp + 1] + si_[g] * sjA[t2i][2 * hp + 1];
                        float pl = __builtin_amdgcn_exp2f(sc[g][t2i][2 * hp]     * wl);
                        float ph = __builtin_amdgcn_exp2f(sc[g][t2i][2 * hp + 1] * wh);
                        unsigned int w;
                        asm("v_cvt_pk_bf16_f32 %0, %1, %2" : "=v"(w) : "v"(pl), "v"(ph));
                        w_[t2i * 2 + hp] = w;
                    }
                }
                auto t02 = __builtin_amdgcn_permlane32_swap(w_[0], w_[2], false, false);
                auto a02 = __builtin_amdgcn_permlane16_swap(t02[0], t02[1], false, false);
                auto t13 = __builtin_amdgcn_permlane32_swap(w_[1], w_[3], false, false);
                auto a13 = __builtin_amdgcn_permlane16_swap(t13[0], t13[1], false, false);
                uint4v pword;
                pword[0] = a02[0]; pword[1] = a13[0]; pword[2] = a02[1]; pword[3] = a13[1];
                pa[g] = __builtin_bit_cast(short8, pword);   // A[row=q l15][k=quad*8+e]
                accden[g] = mfma16(pa[g], ones, accden[g]);
            }

            __builtin_amdgcn_s_setprio(1);
#pragma unroll
            for (int dt = 0; dt < 4; dt++) {
                int ch = (chunk * 4 + quad) ^ l15;
                short8 vb = *(const short8*)(Vme + (dt * 16 + l15) * KT + ch * 8);
                acc[0][dt] = mfma16(pa[0], vb, acc[0][dt]);
                acc[1][dt] = mfma16(pa[1], vb, acc[1][dt]);
            }
            __builtin_amdgcn_s_setprio(0);
        }
        __syncthreads();                 // all reads done before next stage overwrites
    }

    // ---- key-half combine through (dead) staging LDS; stride 41 floats = conflict-free
    float* cmb = (float*)sbuf;
    const int slot = (w4 * 64 + lane) * 41;
    if (kh == 1) {
#pragma unroll
        for (int g = 0; g < 2; g++) {
#pragma unroll
            for (int dt = 0; dt < 4; dt++)
#pragma unroll
                for (int r = 0; r < 4; r++)
                    cmb[slot + g * 16 + dt * 4 + r] = acc[g][dt][r];
#pragma unroll
            for (int r = 0; r < 4; r++)
                cmb[slot + 32 + g * 4 + r] = accden[g][r];
        }
    }
    __syncthreads();
    if (kh == 0) {
#pragma unroll
        for (int g = 0; g < 2; g++) {
#pragma unroll
            for (int dt = 0; dt < 4; dt++)
#pragma unroll
                for (int r = 0; r < 4; r++)
                    acc[g][dt][r] += cmb[slot + g * 16 + dt * 4 + r];
#pragma unroll
            for (int r = 0; r < 4; r++)
                accden[g][r] += cmb[slot + 32 + g * 4 + r];
        }
#pragma unroll
        for (int g = 0; g < 2; g++) {
            float rinv[4];
#pragma unroll
            for (int r = 0; r < 4; r++) rinv[r] = 1.0f / accden[g][r];
#pragma unroll
            for (int dt = 0; dt < 4; dt++) {
#pragma unroll
                for (int r = 0; r < 4; r++) {
                    int q = q0 + g * 16 + quad * 4 + r;
                    int d = dt * 16 + l15;
                    Ob[((size_t)(b * SEQ + q)) * HIDDEN + h * 64 + d] = f2bf(acc[g][dt][r] * rinv[r]);
                }
            }
        }
    }
}

// ---------------------------------------------------------------- launch
extern "C" void kernel_launch(void* const* d_in, const int* in_sizes, int n_in,
                              void* d_out, int out_size, void* d_ws, size_t ws_size,
                              hipStream_t stream) {
    const float* x  = (const float*)d_in[0];
    const float* Wq = (const float*)d_in[1];
    const float* Wk = (const float*)d_in[2];
    const float* Wv = (const float*)d_in[3];
    const float* Wo = (const float*)d_in[4];
    const float* qp = (const float*)d_in[5];
    const float* qa = (const float*)d_in[6];
    char* ws = (char*)d_ws;

    unsigned short* Xb  = (unsigned short*)(ws);                      // 8 MB (reused as Ob)
    unsigned short* Wt  = (unsigned short*)(ws + (size_t)( 8 << 20)); // 8 MB (4 x 2MB)
    unsigned short* Cq  = (unsigned short*)(ws + (size_t)(16 << 20)); // 8 MB
    unsigned short* Ck  = (unsigned short*)(ws + (size_t)(24 << 20)); // 8 MB
    unsigned short* Cv  = (unsigned short*)(ws + (size_t)(32 << 20)); // 8 MB (holds V*mod)
    unsigned short* Vpt = (unsigned short*)(ws + (size_t)(40 << 20)); // 8 MB
    float* mod  = (float*)(ws + (size_t)(48 << 20));
    float* mod2 = mod + 1024;
    float* posc = mod2 + 1024;
    float* poss = posc + 2048;
    float* out  = (float*)d_out;

    prep_kernel<<<5120, 256, 0, stream>>>(x, Xb, Wq, Wk, Wv, Wo, Wt,
                                          qp, qa, mod, mod2, posc, poss);
    gemm_kernel<<<dim3(32, 16), 256, 0, stream>>>(Xb, Wt, Cq, mod);  // fused -> Cq,Ck,Cv(modded)
    vshift_kernel<<<dim3(32, 32), 256, 0, stream>>>(Cv, Vpt);
    attn_kernel<<<dim3(32, 16), 512, 0, stream>>>(Cq, Ck, Vpt, Xb /*Ob*/, mod2, posc, poss);
    gemm_o_kernel<<<dim3(32, 16), 256, 0, stream>>>(Xb, Wt + (size_t)3 * HIDDEN * HIDDEN, out);
}